// Round 1
// baseline (657.731 us; speedup 1.0000x reference)
//
#include <hip/hip_runtime.h>

// LabelSmoothing: x [N=4096, V=32000] fp32, target [N] int.
//   out = 0.1 * (-sum(x[valid rows])) / V + 0.9 * (-sum(x[i, target[i]], valid))
//
// Memory-bound streaming reduce (524 MB read once). One block per row.
// R5 changes vs R4:
//  - PLAIN cached float4 loads instead of __builtin_nontemporal_load.
//    The 6.4 TB/s fill in this very run and the m13 copy ceiling both use
//    cached vector ops; NT evict-first/bypass is the prime suspect for the
//    measured 1.77 TB/s read rate.
//  - block = 320 threads: 8000 float4/row = 320 x 25 exactly. Every thread
//    does 25 loads, no tail, no divergent `if (tid < 64)`.
//  - 5 independent float4 vector accumulators, loads batched 5-at-a-time and
//    fully unrolled -> deep MLP per wave, short dependency chains (no
//    horizontal-add in the hot loop).
//  - kept from R4: early wave-uniform gather of x[row, t] so its HBM latency
//    hides under the stream; mask applied multiplicatively at the end.

#define LS_V 32000
#define LS_SMOOTH 0.1f

typedef float f4 __attribute__((ext_vector_type(4)));

__global__ __launch_bounds__(320) void ls_row_reduce(
    const float* __restrict__ x,
    const int*   __restrict__ target,
    float*       __restrict__ partial)
{
    const int row = blockIdx.x;
    const int tid = threadIdx.x;

    const int t = target[row];                 // wave-uniform scalar load
    // Early gather: always in-bounds (t in [0,V)), whole block hits one line.
    const float g = x[(size_t)row * LS_V + t];

    const f4* __restrict__ xr = (const f4*)(x + (size_t)row * LS_V);

    // 8000 float4 = 320 threads * 25. Five independent accumulator streams.
    f4 a0 = {0.f, 0.f, 0.f, 0.f};
    f4 a1 = a0, a2 = a0, a3 = a0, a4 = a0;

    #pragma unroll
    for (int i = 0; i < 25; i += 5) {
        f4 v0 = xr[tid + (i + 0) * 320];
        f4 v1 = xr[tid + (i + 1) * 320];
        f4 v2 = xr[tid + (i + 2) * 320];
        f4 v3 = xr[tid + (i + 3) * 320];
        f4 v4 = xr[tid + (i + 4) * 320];
        a0 += v0;
        a1 += v1;
        a2 += v2;
        a3 += v3;
        a4 += v4;
    }

    f4 av = ((a0 + a1) + (a2 + a3)) + a4;
    float s = (av.x + av.y) + (av.z + av.w);

    #pragma unroll
    for (int off = 32; off > 0; off >>= 1)
        s += __shfl_down(s, off, 64);

    __shared__ float wsum[5];                  // 320 threads = 5 waves
    if ((tid & 63) == 0) wsum[tid >> 6] = s;
    __syncthreads();

    if (tid == 0) {
        const float S = (((wsum[0] + wsum[1]) + (wsum[2] + wsum[3])) + wsum[4]);
        const float maskf = (t != 0) ? 1.0f : 0.0f;   // PADDING_IDX == 0
        partial[row] = maskf * (-(LS_SMOOTH / (float)LS_V) * S
                                - (1.0f - LS_SMOOTH) * g);
    }
}

__global__ __launch_bounds__(256) void ls_final(
    const float* __restrict__ partial,
    float*       __restrict__ out,
    int n)
{
    const int tid = threadIdx.x;
    const int n4 = n >> 2;                     // n = 4096 -> 1024 float4
    const f4* __restrict__ p4 = (const f4*)partial;

    f4 acc = {0.f, 0.f, 0.f, 0.f};
    for (int i = tid; i < n4; i += 256) acc += p4[i];
    float s = (acc.x + acc.y) + (acc.z + acc.w);
    // remainder (none for n = 4096, kept for safety)
    for (int i = (n4 << 2) + tid; i < n; i += 256) s += partial[i];

    #pragma unroll
    for (int off = 32; off > 0; off >>= 1)
        s += __shfl_down(s, off, 64);

    __shared__ float wsum[4];
    if ((tid & 63) == 0) wsum[tid >> 6] = s;
    __syncthreads();
    if (tid == 0) out[0] = (wsum[0] + wsum[1]) + (wsum[2] + wsum[3]);
}

extern "C" void kernel_launch(void* const* d_in, const int* in_sizes, int n_in,
                              void* d_out, int out_size, void* d_ws, size_t ws_size,
                              hipStream_t stream)
{
    const float* x      = (const float*)d_in[0];   // [4096, 32000] fp32
    const int*   target = (const int*)d_in[1];     // [4096] int
    float*       out    = (float*)d_out;           // scalar fp32
    float*       part   = (float*)d_ws;            // 4096 fp32 partials

    const int N = in_sizes[1];                     // 4096 rows

    ls_row_reduce<<<N, 320, 0, stream>>>(x, target, part);
    ls_final<<<1, 256, 0, stream>>>(part, out, N);
}

// Round 2
// 644.807 us; speedup vs baseline: 1.0200x; 1.0200x over previous
//
#include <hip/hip_runtime.h>

// LabelSmoothing: x [N=4096, V=32000] fp32, target [N] int.
//   out = 0.1 * (-sum(x[valid rows])) / V + 0.9 * (-sum(x[i, target[i]], valid))
//
// R6: THE ACCESS-PATTERN RESTRUCTURE.
// R0-R5 all used one-block-per-row => ~2000 resident waves each streaming its
// own scattered 125KB region => ~1.7 TB/s. The harness's own fillBuffer hits
// 6.4 TB/s in the same run using a single linear sweep (whole grid walks one
// contiguous moving window). This version adopts the sweep pattern:
//
//   - flat grid-stride over the 32M-float4 array; at any instant the grid
//     touches one contiguous ~8MB window (DRAM page/bank friendly).
//   - 8000 f4 per row = exactly 125 wave-chunks of 64 f4 => a wave-aligned
//     chunk NEVER crosses a row boundary. Each wave reduces its 1KB chunk
//     (6 shfl) and lane 0 writes chunksum[chunk]. No atomics, deterministic.
//   - finish1: thread r sums its row's 125 contiguous chunk-sums (2MB,
//     L2-resident), adds the gather term, applies the padding mask.
//   - finish2: sums the 16 block results.

#define LS_V      32000
#define LS_V4     8000          // float4 per row
#define LS_SMOOTH 0.1f

#define SW_BLOCKS  2000
#define SW_THREADS 256
#define SW_TOTAL   (SW_BLOCKS * SW_THREADS)   // 512000 threads

typedef float f4 __attribute__((ext_vector_type(4)));

__global__ __launch_bounds__(SW_THREADS) void ls_sweep(
    const float* __restrict__ x,
    float*       __restrict__ chunksum,   // one float per 64-f4 wave chunk
    int nf4)                              // N * 8000
{
    const int g    = blockIdx.x * SW_THREADS + threadIdx.x;
    const int lane = threadIdx.x & 63;
    const f4* __restrict__ x4 = (const f4*)x;

    #pragma unroll 4
    for (int f4idx = g; f4idx < nf4; f4idx += SW_TOTAL) {
        f4 v = __builtin_nontemporal_load(&x4[f4idx]);
        float s = (v.x + v.y) + (v.z + v.w);
        #pragma unroll
        for (int off = 32; off > 0; off >>= 1)
            s += __shfl_down(s, off, 64);
        if (lane == 0)
            chunksum[f4idx >> 6] = s;     // lane0's f4idx is the wave base
    }
}

// One thread per row: combine 125 chunk sums + gather term + mask.
__global__ __launch_bounds__(256) void ls_finish1(
    const float* __restrict__ x,
    const int*   __restrict__ target,
    const float* __restrict__ chunksum,
    float*       __restrict__ bsum)
{
    const int tid = threadIdx.x;
    const int r   = blockIdx.x * 256 + tid;

    const int   t = target[r];
    const float g = x[(size_t)r * LS_V + t];

    const float* __restrict__ cs = chunksum + r * (LS_V4 / 64);  // 125 per row
    float rs = 0.0f;
    #pragma unroll 5
    for (int i = 0; i < (LS_V4 / 64); ++i) rs += cs[i];

    float s = (t != 0) ? (-(LS_SMOOTH / (float)LS_V) * rs
                          - (1.0f - LS_SMOOTH) * g)
                       : 0.0f;

    #pragma unroll
    for (int off = 32; off > 0; off >>= 1)
        s += __shfl_down(s, off, 64);

    __shared__ float wsum[4];
    if ((tid & 63) == 0) wsum[tid >> 6] = s;
    __syncthreads();
    if (tid == 0)
        bsum[blockIdx.x] = (wsum[0] + wsum[1]) + (wsum[2] + wsum[3]);
}

__global__ __launch_bounds__(64) void ls_finish2(
    const float* __restrict__ bsum,
    float*       __restrict__ out,
    int nb)
{
    const int tid = threadIdx.x;
    float s = (tid < nb) ? bsum[tid] : 0.0f;
    #pragma unroll
    for (int off = 32; off > 0; off >>= 1)
        s += __shfl_down(s, off, 64);
    if (tid == 0) out[0] = s;
}

extern "C" void kernel_launch(void* const* d_in, const int* in_sizes, int n_in,
                              void* d_out, int out_size, void* d_ws, size_t ws_size,
                              hipStream_t stream)
{
    const float* x      = (const float*)d_in[0];   // [4096, 32000] fp32
    const int*   target = (const int*)d_in[1];     // [4096] int
    float*       out    = (float*)d_out;           // scalar fp32

    const int N    = in_sizes[1];                  // 4096 rows
    const int nf4  = N * LS_V4;                    // 32,768,000 float4
    const int nchk = nf4 >> 6;                     // 512,000 chunk sums
    const int nb   = N / 256;                      // 16 finish1 blocks

    float* chunksum = (float*)d_ws;                // 2 MB
    float* bsum     = chunksum + nchk;             // 64 floats

    ls_sweep  <<<SW_BLOCKS, SW_THREADS, 0, stream>>>(x, chunksum, nf4);
    ls_finish1<<<nb,        256,        0, stream>>>(x, target, chunksum, bsum);
    ls_finish2<<<1,         64,         0, stream>>>(bsum, out, nb);
}